// Round 9
// baseline (3257.898 us; speedup 1.0000x reference)
//
#include <hip/hip_runtime.h>

// Problem constants
#define NB 8
#define NT 1024
#define ND 768     // = 12*64
#define NH 12
#define NU 64
#define BT (NB*NT)   // 8192
#define SCALE32 ((float)0.03608439182435161)  // fp32(768^-0.5)
#define EPS32 1e-7f

// ---------------------------------------------------------------------------
// numpy baseline-SIMD (SSE2, no FMA) einsum dot over 64 contiguous elements:
// 4 accumulators stride-4, separate mul/add (rounded each), reduce
// (r0+r2)+(r1+r3) [movehl npyv_sum]. __f*_rn blocks hipcc contraction.
// Used bitwise-identically wherever scores are computed.
// ---------------------------------------------------------------------------
__device__ __forceinline__ float dot64_np(const float* a, const float* b)
{
    float r[4];
#pragma unroll
    for (int j = 0; j < 4; j++) r[j] = __fmul_rn(a[j], b[j]);
#pragma unroll
    for (int i = 1; i < 16; i++)
#pragma unroll
        for (int j = 0; j < 4; j++)
            r[j] = __fadd_rn(r[j], __fmul_rn(a[i * 4 + j], b[i * 4 + j]));
    return __fadd_rn(__fadd_rn(r[0], r[2]), __fadd_rn(r[1], r[3]));
}

// ---------------------------------------------------------------------------
// Mask decode with byte/int32 layout sniff (mask is all-ones in practice).
// ---------------------------------------------------------------------------
__global__ __launch_bounds__(256) void mask_k(
    const unsigned char* __restrict__ mb, float* __restrict__ mf)
{
    __shared__ int cntOff, cntAll;
    if (threadIdx.x == 0) { cntOff = 0; cntAll = 0; }
    __syncthreads();
    int lo = 0, la = 0;
    for (int i = threadIdx.x; i < BT; i += 256)
        if (mb[i] != 0) { la++; if ((i & 3) != 0) lo++; }
    atomicAdd(&cntOff, lo);
    atomicAdd(&cntAll, la);
    __syncthreads();
    const bool int32mode = (cntOff == 0) && (cntAll != 0);
    if (int32mode) {
        const int* mi = (const int*)mb;
        for (int i = threadIdx.x; i < BT; i += 256)
            mf[i] = (mi[i] != 0) ? 1.f : 0.f;
    } else {
        for (int i = threadIdx.x; i < BT; i += 256)
            mf[i] = (mb[i] != 0) ? 1.f : 0.f;
    }
}

// ---------------------------------------------------------------------------
// OpenBLAS-mimic sgemm: C = A[8192x768] @ W[768x768] (+R elementwise after).
// kc=384 panel split: C = fmachain(k<384) + fmachain(k>=384), each panel's
// microkernel ascending-k fmaf (AVX2 FMA microkernel model). grid (128,12).
// ---------------------------------------------------------------------------
__global__ __launch_bounds__(256) void gemmseq(
    const float* __restrict__ A, const float* __restrict__ W,
    const float* __restrict__ R, float* __restrict__ C)
{
    __shared__ float sA[64][65];   // [m][k]
    __shared__ float sB[64][65];   // [k][n]

    const int t = threadIdx.x;
    const int mbase = blockIdx.x * 64;
    const int nbase = blockIdx.y * 64;
    const int m0 = (t >> 4) * 4;
    const int n0 = (t & 15) * 4;

    float acc[4][4], accA[4][4];
#pragma unroll
    for (int i = 0; i < 4; i++)
#pragma unroll
        for (int j = 0; j < 4; j++) { acc[i][j] = 0.f; accA[i][j] = 0.f; }

    for (int k0 = 0; k0 < 768; k0 += 64) {
        __syncthreads();
#pragma unroll
        for (int i = 0; i < 16; i++) {
            const int idx = t + i * 256;
            const int m = idx >> 6, kk = idx & 63;
            sA[m][kk] = A[(size_t)(mbase + m) * 768 + k0 + kk];
            sB[kk][m] = W[(size_t)(k0 + kk) * 768 + nbase + m];
        }
        __syncthreads();

        for (int kk = 0; kk < 64; kk++) {
            float av[4], bv[4];
#pragma unroll
            for (int i = 0; i < 4; i++) av[i] = sA[m0 + i][kk];
#pragma unroll
            for (int j = 0; j < 4; j++) bv[j] = sB[kk][n0 + j];
#pragma unroll
            for (int i = 0; i < 4; i++)
#pragma unroll
                for (int j = 0; j < 4; j++)
                    acc[i][j] = fmaf(av[i], bv[j], acc[i][j]);
        }

        if (k0 + 64 == 384) {   // end of first kc panel
#pragma unroll
            for (int i = 0; i < 4; i++)
#pragma unroll
                for (int j = 0; j < 4; j++) {
                    accA[i][j] = acc[i][j];
                    acc[i][j] = 0.f;
                }
        }
    }

#pragma unroll
    for (int i = 0; i < 4; i++)
#pragma unroll
        for (int j = 0; j < 4; j++) {
            const size_t idx = (size_t)(mbase + m0 + i) * 768 + nbase + n0 + j;
            float o = __fadd_rn(accA[i][j], acc[i][j]);  // C = panel0 + panel1
            if (R) o = __fadd_rn(o, R[idx]);             // np: out = tmp + x
            C[idx] = o;
        }
}

// ---------------------------------------------------------------------------
// Denominator: D[bh][t] = numpy pairwise_sum over s of
// ((q.k)*scale)*mk*mq, fp32. n=1024: 8 base-128 blocks (8 plain-add
// accumulators) + tree ((B0+B1)+(B2+B3))+((B4+B5)+(B6+B7)).
// One thread per t-row. grid (4, 96) x 256.
// ---------------------------------------------------------------------------
__global__ __launch_bounds__(256) void denom_np(
    const float* __restrict__ Q, const float* __restrict__ K,
    const float* __restrict__ MF, float* __restrict__ D)
{
    __shared__ float sk[128][65];
    __shared__ float smk[128];

    const int bh = blockIdx.y;
    const int b = bh / NH, h = bh % NH;
    const int t = threadIdx.x;
    const int row = blockIdx.x * 256 + t;       // 0..1023
    const float mq = MF[b * NT + row];

    float qr[64];
#pragma unroll
    for (int u = 0; u < 64; u++)
        qr[u] = Q[((size_t)(b * NT + row)) * ND + h * 64 + u];

    float Bi[8];

    for (int c = 0; c < 8; c++) {               // 8 chunks of 128 s
        __syncthreads();
#pragma unroll
        for (int i = 0; i < 32; i++) {
            const int idx = t + i * 256;        // 0..8191
            const int s = idx >> 6, u = idx & 63;
            sk[s][u] = K[((size_t)(b * NT + c * 128 + s)) * ND + h * 64 + u];
        }
        if (t < 128) smk[t] = MF[b * NT + c * 128 + t];
        __syncthreads();

        float b8[8];
        for (int s = 0; s < 128; s++) {
            const float dt = dot64_np(qr, &sk[s][0]);
            float sc = __fmul_rn(dt, SCALE32);  // np: einsum * scale
            sc = __fmul_rn(sc, smk[s]);         // * mask_keys
            sc = __fmul_rn(sc, mq);             // * mask_queries
            const int j = s & 7;
            if (s < 8) b8[j] = sc;
            else       b8[j] = __fadd_rn(b8[j], sc);
        }
        Bi[c] = __fadd_rn(__fadd_rn(__fadd_rn(b8[0], b8[1]), __fadd_rn(b8[2], b8[3])),
                          __fadd_rn(__fadd_rn(b8[4], b8[5]), __fadd_rn(b8[6], b8[7])));
    }

    const float Dv = __fadd_rn(
        __fadd_rn(__fadd_rn(Bi[0], Bi[1]), __fadd_rn(Bi[2], Bi[3])),
        __fadd_rn(__fadd_rn(Bi[4], Bi[5]), __fadd_rn(Bi[6], Bi[7])));
    D[(size_t)bh * NT + row] = Dv;
}

// ---------------------------------------------------------------------------
// Attention out: A[t, h*64+u] = sum_s p_ts * v[s][u], p = sc/(D_t+eps),
// s ascending (np einsum axpy order), mul+add (no fma, SSE2 baseline),
// scores recomputed bitwise-identically to denom_np. A aliases Q (safe:
// block stages its own q-tile before overwrite). grid (16, 96) x 256.
// ---------------------------------------------------------------------------
__global__ __launch_bounds__(256) void attn_np(
    const float* __restrict__ K, const float* __restrict__ V,
    const float* __restrict__ D, const float* __restrict__ MF,
    float* __restrict__ QA)   // in: Q, out: A (aliased)
{
    __shared__ float sq[64][65];
    __shared__ float sk[64][65];
    __shared__ float sv[64][65];
    __shared__ float sp[64][65];
    __shared__ float sDe[64];   // D_t + eps
    __shared__ float smq[64];
    __shared__ float smk[64];

    const int bh = blockIdx.y;
    const int b = bh / NH, h = bh % NH;
    const int r0 = blockIdx.x * 64;             // t-tile base within batch
    const int t = threadIdx.x;

#pragma unroll
    for (int i = 0; i < 16; i++) {
        const int idx = t + i * 256;
        const int r = idx >> 6, u = idx & 63;
        sq[r][u] = QA[((size_t)(b * NT + r0 + r)) * ND + h * 64 + u];
    }
    if (t < 64) {
        sDe[t] = __fadd_rn(D[(size_t)bh * NT + r0 + t], EPS32);  // np: sum+eps
        smq[t] = MF[b * NT + r0 + t];
    }
    __syncthreads();

    const int tq = t >> 2;           // score row 0..63
    const int sg = (t & 3) * 16;     // score col group
    const int ta = t & 63;           // accum row
    const int u0 = (t >> 6) * 16;    // accum col group

    float o[16];
#pragma unroll
    for (int j = 0; j < 16; j++) o[j] = 0.f;

    for (int c = 0; c < 16; c++) {              // s-chunks of 64, ascending
        __syncthreads();
#pragma unroll
        for (int i = 0; i < 16; i++) {
            const int idx = t + i * 256;
            const int s = idx >> 6, u = idx & 63;
            const size_t g = ((size_t)(b * NT + c * 64 + s)) * ND + h * 64 + u;
            sk[s][u] = K[g];
            sv[s][u] = V[g];
        }
        if (t < 64) smk[t] = MF[b * NT + c * 64 + t];
        __syncthreads();

        // scores -> p for this chunk (bitwise same score math as denom_np)
        for (int ss = sg; ss < sg + 16; ss++) {
            const float dt = dot64_np(&sq[tq][0], &sk[ss][0]);
            float sc = __fmul_rn(dt, SCALE32);
            sc = __fmul_rn(sc, smk[ss]);
            sc = __fmul_rn(sc, smq[tq]);
            sp[tq][ss] = __fdiv_rn(sc, sDe[tq]);
        }
        __syncthreads();

        // accumulate p*v, s ascending, mul+add (np SSE2 axpy)
        for (int s = 0; s < 64; s++) {
            const float pv = sp[ta][s];
#pragma unroll
            for (int j = 0; j < 16; j++)
                o[j] = __fadd_rn(o[j], __fmul_rn(pv, sv[s][u0 + j]));
        }
    }

    __syncthreads();
#pragma unroll
    for (int j = 0; j < 16; j++)
        QA[((size_t)(b * NT + r0 + ta)) * ND + h * 64 + u0 + j] = o[j];
}

// ---------------------------------------------------------------------------
// Row norm, numpy-faithful: mean = pairwise_sum_768(row)/768 (8 base-96
// blocks, plain adds, tree combine), then gamma*(v-mean)/(mean+eps)+beta
// elementwise fp32 in np order. One thread per row. grid 32 x 256.
// ---------------------------------------------------------------------------
__global__ __launch_bounds__(256) void rownorm_np(
    float* __restrict__ Y, const float* __restrict__ gamma,
    const float* __restrict__ beta)
{
    const int row = blockIdx.x * 256 + threadIdx.x;
    float* yr = Y + (size_t)row * ND;

    float Ci[8];
    for (int c = 0; c < 8; c++) {               // base-96 blocks
        const float* a = yr + c * 96;
        float r8[8];
#pragma unroll
        for (int j = 0; j < 8; j++) r8[j] = a[j];
        for (int i = 1; i < 12; i++)
#pragma unroll
            for (int j = 0; j < 8; j++) r8[j] = __fadd_rn(r8[j], a[i * 8 + j]);
        Ci[c] = __fadd_rn(__fadd_rn(__fadd_rn(r8[0], r8[1]), __fadd_rn(r8[2], r8[3])),
                          __fadd_rn(__fadd_rn(r8[4], r8[5]), __fadd_rn(r8[6], r8[7])));
    }
    const float S = __fadd_rn(
        __fadd_rn(__fadd_rn(Ci[0], Ci[1]), __fadd_rn(Ci[2], Ci[3])),
        __fadd_rn(__fadd_rn(Ci[4], Ci[5]), __fadd_rn(Ci[6], Ci[7])));
    const float m = __fdiv_rn(S, 768.0f);
    const float mpe = __fadd_rn(m, EPS32);

    for (int j = 0; j < 768; j++) {
        const float v = yr[j];
        float o = __fsub_rn(v, m);
        o = __fmul_rn(gamma[j], o);
        o = __fdiv_rn(o, mpe);
        o = __fadd_rn(o, beta[j]);
        yr[j] = o;
    }
}

// ---------------------------------------------------------------------------
extern "C" void kernel_launch(void* const* d_in, const int* in_sizes, int n_in,
                              void* d_out, int out_size, void* d_ws, size_t ws_size,
                              hipStream_t stream)
{
    (void)in_sizes; (void)n_in; (void)out_size; (void)ws_size;
    const float* x     = (const float*)d_in[0];
    const unsigned char* maskb = (const unsigned char*)d_in[1];
    const float* wq    = (const float*)d_in[2];
    const float* wk    = (const float*)d_in[3];
    const float* wv    = (const float*)d_in[4];
    const float* wf    = (const float*)d_in[5];
    const float* gamma = (const float*)d_in[6];
    const float* beta  = (const float*)d_in[7];

    float* ws = (float*)d_ws;
    float* MF = ws;                             // 8192
    float* D  = MF + BT;                        // 96*1024
    float* Q  = D + (size_t)96 * NT;            // 8192*768 (becomes A)
    float* K  = Q + (size_t)BT * ND;            // 8192*768
    float* V  = K + (size_t)BT * ND;            // 8192*768
    float* Y  = (float*)d_out;                  // total ws: 75.9 MB

    mask_k<<<1, 256, 0, stream>>>(maskb, MF);
    gemmseq<<<dim3(128, 12), 256, 0, stream>>>(x, wq, nullptr, Q);
    gemmseq<<<dim3(128, 12), 256, 0, stream>>>(x, wk, nullptr, K);
    gemmseq<<<dim3(128, 12), 256, 0, stream>>>(x, wv, nullptr, V);
    denom_np<<<dim3(4, 96), 256, 0, stream>>>(Q, K, MF, D);
    attn_np<<<dim3(16, 96), 256, 0, stream>>>(K, V, D, MF, Q);  // Q -> A
    gemmseq<<<dim3(128, 12), 256, 0, stream>>>(Q, wf, x, Y);
    rownorm_np<<<32, 256, 0, stream>>>(Y, gamma, beta);
}

// Round 10
// 1914.936 us; speedup vs baseline: 1.7013x; 1.7013x over previous
//
#include <hip/hip_runtime.h>

// Problem constants
#define NB 8
#define NT 1024
#define ND 768     // = 12*64
#define NH 12
#define NU 64
#define BT (NB*NT)   // 8192
#define SCALE32 ((float)0.03608439182435161)  // fp32(768^-0.5)
#define EPS32 1e-7f

// ---------------------------------------------------------------------------
// numpy baseline-SIMD (SSE2, no FMA) einsum dot over 64 contiguous elements:
// 4 accumulators stride-4, separate mul/add (rounded each), reduce
// (r0+r2)+(r1+r3). __f*_rn blocks hipcc contraction. BITWISE-IDENTICAL to R9.
// ---------------------------------------------------------------------------
__device__ __forceinline__ float dot64_np(const float* a, const float* b)
{
    float r[4];
#pragma unroll
    for (int j = 0; j < 4; j++) r[j] = __fmul_rn(a[j], b[j]);
#pragma unroll
    for (int i = 1; i < 16; i++)
#pragma unroll
        for (int j = 0; j < 4; j++)
            r[j] = __fadd_rn(r[j], __fmul_rn(a[i * 4 + j], b[i * 4 + j]));
    return __fadd_rn(__fadd_rn(r[0], r[2]), __fadd_rn(r[1], r[3]));
}

// ---------------------------------------------------------------------------
// Mask decode with byte/int32 layout sniff (mask is all-ones in practice).
// ---------------------------------------------------------------------------
__global__ __launch_bounds__(256) void mask_k(
    const unsigned char* __restrict__ mb, float* __restrict__ mf)
{
    __shared__ int cntOff, cntAll;
    if (threadIdx.x == 0) { cntOff = 0; cntAll = 0; }
    __syncthreads();
    int lo = 0, la = 0;
    for (int i = threadIdx.x; i < BT; i += 256)
        if (mb[i] != 0) { la++; if ((i & 3) != 0) lo++; }
    atomicAdd(&cntOff, lo);
    atomicAdd(&cntAll, la);
    __syncthreads();
    const bool int32mode = (cntOff == 0) && (cntAll != 0);
    if (int32mode) {
        const int* mi = (const int*)mb;
        for (int i = threadIdx.x; i < BT; i += 256)
            mf[i] = (mi[i] != 0) ? 1.f : 0.f;
    } else {
        for (int i = threadIdx.x; i < BT; i += 256)
            mf[i] = (mb[i] != 0) ? 1.f : 0.f;
    }
}

// ---------------------------------------------------------------------------
// OpenBLAS-mimic sgemm: C = A[8192x768] @ W[768x768] (+R elementwise after).
// kc=384 panel split preserved bitwise. LDS now b128-friendly: sA transposed
// to [k][m] (pad 68 keeps 16B alignment), microkernel does 2x ds_read_b128
// per kk instead of 8x b32. Arithmetic chains unchanged. grid (128,12).
// ---------------------------------------------------------------------------
__global__ __launch_bounds__(256) void gemmseq(
    const float* __restrict__ A, const float* __restrict__ W,
    const float* __restrict__ R, float* __restrict__ C)
{
    __shared__ float sA[64][68];   // [k][m], transposed, pad 68 (16B-aligned rows)
    __shared__ float sB[64][68];   // [k][n]

    const int t = threadIdx.x;
    const int mbase = blockIdx.x * 64;
    const int nbase = blockIdx.y * 64;
    const int m0 = (t >> 4) * 4;
    const int n0 = (t & 15) * 4;

    float acc[4][4], accA[4][4];
#pragma unroll
    for (int i = 0; i < 4; i++)
#pragma unroll
        for (int j = 0; j < 4; j++) { acc[i][j] = 0.f; accA[i][j] = 0.f; }

    for (int k0 = 0; k0 < 768; k0 += 64) {
        __syncthreads();
#pragma unroll
        for (int i = 0; i < 4; i++) {
            const int idx = t + i * 256;          // 0..1023
            const int mr = idx >> 4;              // 0..63
            const int k4 = (idx & 15) * 4;        // 0..60
            const float4 a4 = *(const float4*)&A[(size_t)(mbase + mr) * 768 + k0 + k4];
            sA[k4 + 0][mr] = a4.x;
            sA[k4 + 1][mr] = a4.y;
            sA[k4 + 2][mr] = a4.z;
            sA[k4 + 3][mr] = a4.w;
            *(float4*)&sB[mr][k4] =
                *(const float4*)&W[(size_t)(k0 + mr) * 768 + nbase + k4];
        }
        __syncthreads();

        for (int kk = 0; kk < 64; kk++) {
            float av[4], bv[4];
            *(float4*)&av[0] = *(const float4*)&sA[kk][m0];
            *(float4*)&bv[0] = *(const float4*)&sB[kk][n0];
#pragma unroll
            for (int i = 0; i < 4; i++)
#pragma unroll
                for (int j = 0; j < 4; j++)
                    acc[i][j] = fmaf(av[i], bv[j], acc[i][j]);
        }

        if (k0 + 64 == 384) {   // end of first kc panel (OpenBLAS kc=384)
#pragma unroll
            for (int i = 0; i < 4; i++)
#pragma unroll
                for (int j = 0; j < 4; j++) {
                    accA[i][j] = acc[i][j];
                    acc[i][j] = 0.f;
                }
        }
    }

#pragma unroll
    for (int i = 0; i < 4; i++)
#pragma unroll
        for (int j = 0; j < 4; j++) {
            const size_t idx = (size_t)(mbase + m0 + i) * 768 + nbase + n0 + j;
            float o = __fadd_rn(accA[i][j], acc[i][j]);  // C = panel0 + panel1
            if (R) o = __fadd_rn(o, R[idx]);             // np: out = tmp + x
            C[idx] = o;
        }
}

// ---------------------------------------------------------------------------
// Denominator: D[bh][t] = numpy pairwise_sum over s (8 base-128 blocks of
// 8 plain-add accumulators + tree). One THREAD per row, q in registers,
// k via wave-uniform scalar loads (readfirstlane-proven) — zero LDS.
// grid 768 x 128. Arithmetic bitwise-identical to R9.
// ---------------------------------------------------------------------------
__global__ __launch_bounds__(128) void denom_np(
    const float* __restrict__ Q, const float* __restrict__ K,
    const float* __restrict__ MF, float* __restrict__ D)
{
    const int gid = blockIdx.x * 128 + threadIdx.x;  // 0..98303
    const int bh = gid >> 10;                        // uniform per block
    const int row = gid & 1023;
    const int b = bh / NH, h = bh % NH;
    const int bh_u = __builtin_amdgcn_readfirstlane(bh);
    const int b_u = bh_u / NH, h_u = bh_u % NH;

    const float mq = MF[b * NT + row];

    float qr[64];
    const float4* qp = (const float4*)&Q[((size_t)(b * NT + row)) * ND + h * 64];
#pragma unroll
    for (int i = 0; i < 16; i++) *(float4*)&qr[i * 4] = qp[i];

    const float* Kb = &K[((size_t)(b_u * NT)) * ND + h_u * 64];
    const float* MFb = &MF[b_u * NT];

    float Bi[8];
    for (int c = 0; c < 8; c++) {
        float b8[8];
        for (int s = 0; s < 128; s++) {
            const int sg = c * 128 + s;
            const float dt = dot64_np(qr, Kb + (size_t)sg * ND); // uniform k
            float sc = __fmul_rn(dt, SCALE32);
            sc = __fmul_rn(sc, MFb[sg]);
            sc = __fmul_rn(sc, mq);
            const int j = s & 7;
            if (s < 8) b8[j] = sc;
            else       b8[j] = __fadd_rn(b8[j], sc);
        }
        Bi[c] = __fadd_rn(__fadd_rn(__fadd_rn(b8[0], b8[1]), __fadd_rn(b8[2], b8[3])),
                          __fadd_rn(__fadd_rn(b8[4], b8[5]), __fadd_rn(b8[6], b8[7])));
    }

    D[(size_t)bh * NT + row] = __fadd_rn(
        __fadd_rn(__fadd_rn(Bi[0], Bi[1]), __fadd_rn(Bi[2], Bi[3])),
        __fadd_rn(__fadd_rn(Bi[4], Bi[5]), __fadd_rn(Bi[6], Bi[7])));
}

// ---------------------------------------------------------------------------
// Attention out. One THREAD per row: q (64 regs), o[64] accumulators,
// k/v via wave-uniform scalar loads — zero LDS. Scores recomputed with the
// bitwise-identical dot/mask/scale/divide sequence; o[u] chains over s
// ascending 0..1023 exactly as R9. Self-aliased QA (each row read then
// written by its own thread only). grid 768 x 128.
// ---------------------------------------------------------------------------
__global__ __launch_bounds__(128) void attn_np(
    const float* __restrict__ K, const float* __restrict__ V,
    const float* __restrict__ D, const float* __restrict__ MF,
    float* __restrict__ QA)   // in: Q, out: A (self-aliased per row)
{
    const int gid = blockIdx.x * 128 + threadIdx.x;
    const int bh = gid >> 10;
    const int row = gid & 1023;
    const int b = bh / NH, h = bh % NH;
    const int bh_u = __builtin_amdgcn_readfirstlane(bh);
    const int b_u = bh_u / NH, h_u = bh_u % NH;

    const float mq = MF[b * NT + row];
    const float De = __fadd_rn(D[(size_t)bh * NT + row], EPS32);  // np: sum+eps

    float qr[64];
    const float4* qp = (const float4*)&QA[((size_t)(b * NT + row)) * ND + h * 64];
#pragma unroll
    for (int i = 0; i < 16; i++) *(float4*)&qr[i * 4] = qp[i];

    float o[64];
#pragma unroll
    for (int j = 0; j < 64; j++) o[j] = 0.f;

    const float* Kb = &K[((size_t)(b_u * NT)) * ND + h_u * 64];
    const float* Vb = &V[((size_t)(b_u * NT)) * ND + h_u * 64];
    const float* MFb = &MF[b_u * NT];

    for (int s = 0; s < NT; s++) {
        const float dt = dot64_np(qr, Kb + (size_t)s * ND);  // uniform k
        float sc = __fmul_rn(dt, SCALE32);
        sc = __fmul_rn(sc, MFb[s]);
        sc = __fmul_rn(sc, mq);
        const float p = __fdiv_rn(sc, De);
        const float* vp = Vb + (size_t)s * ND;               // uniform v
#pragma unroll
        for (int j = 0; j < 64; j++)
            o[j] = __fadd_rn(o[j], __fmul_rn(p, vp[j]));     // np SSE2 axpy
    }

    float4* op = (float4*)&QA[((size_t)(b * NT + row)) * ND + h * 64];
#pragma unroll
    for (int i = 0; i < 16; i++) op[i] = *(float4*)&o[i * 4];
}

// ---------------------------------------------------------------------------
// Row norm, numpy-faithful pairwise mean via ONE WAVE per row: lane (c,j)
// runs chain r8[j] of base-96 block c (12 plain adds); xor-butterfly
// reproduces ((r0+r1)+(r2+r3))+((r4+r5)+(r6+r7)) and the Ci tree bitwise
// (fp32 add is commutative). Then elementwise np-order normalize.
// grid 2048 x 256 (4 waves/block).
// ---------------------------------------------------------------------------
__global__ __launch_bounds__(256) void rownorm_np(
    float* __restrict__ Y, const float* __restrict__ gamma,
    const float* __restrict__ beta)
{
    const int wave = threadIdx.x >> 6, lane = threadIdx.x & 63;
    const int row = blockIdx.x * 4 + wave;
    float* yr = Y + (size_t)row * ND;
    const int c = lane >> 3, j = lane & 7;

    const float* a = yr + c * 96;
    float r = a[j];
#pragma unroll
    for (int i = 1; i < 12; i++) r = __fadd_rn(r, a[i * 8 + j]);

    // j-tree within base-96 block, then c-tree across blocks (bitwise = R9)
    r = __fadd_rn(r, __shfl_xor(r, 1, 64));
    r = __fadd_rn(r, __shfl_xor(r, 2, 64));
    r = __fadd_rn(r, __shfl_xor(r, 4, 64));
    r = __fadd_rn(r, __shfl_xor(r, 8, 64));
    r = __fadd_rn(r, __shfl_xor(r, 16, 64));
    r = __fadd_rn(r, __shfl_xor(r, 32, 64));

    const float m = __fdiv_rn(r, 768.0f);
    const float mpe = __fadd_rn(m, EPS32);

#pragma unroll
    for (int i = 0; i < 12; i++) {
        const int idx = i * 64 + lane;
        const float v = yr[idx];
        float o = __fsub_rn(v, m);
        o = __fmul_rn(gamma[idx], o);
        o = __fdiv_rn(o, mpe);
        o = __fadd_rn(o, beta[idx]);
        yr[idx] = o;
    }
}

// ---------------------------------------------------------------------------
extern "C" void kernel_launch(void* const* d_in, const int* in_sizes, int n_in,
                              void* d_out, int out_size, void* d_ws, size_t ws_size,
                              hipStream_t stream)
{
    (void)in_sizes; (void)n_in; (void)out_size; (void)ws_size;
    const float* x     = (const float*)d_in[0];
    const unsigned char* maskb = (const unsigned char*)d_in[1];
    const float* wq    = (const float*)d_in[2];
    const float* wk    = (const float*)d_in[3];
    const float* wv    = (const float*)d_in[4];
    const float* wf    = (const float*)d_in[5];
    const float* gamma = (const float*)d_in[6];
    const float* beta  = (const float*)d_in[7];

    float* ws = (float*)d_ws;
    float* MF = ws;                             // 8192
    float* D  = MF + BT;                        // 96*1024
    float* Q  = D + (size_t)96 * NT;            // 8192*768 (becomes A)
    float* K  = Q + (size_t)BT * ND;            // 8192*768
    float* V  = K + (size_t)BT * ND;            // 8192*768
    float* Y  = (float*)d_out;                  // total ws: 75.9 MB

    mask_k<<<1, 256, 0, stream>>>(maskb, MF);
    gemmseq<<<dim3(128, 12), 256, 0, stream>>>(x, wq, nullptr, Q);
    gemmseq<<<dim3(128, 12), 256, 0, stream>>>(x, wk, nullptr, K);
    gemmseq<<<dim3(128, 12), 256, 0, stream>>>(x, wv, nullptr, V);
    denom_np<<<768, 128, 0, stream>>>(Q, K, MF, D);
    attn_np<<<768, 128, 0, stream>>>(K, V, D, MF, Q);  // Q -> A
    gemmseq<<<dim3(128, 12), 256, 0, stream>>>(Q, wf, x, Y);
    rownorm_np<<<2048, 256, 0, stream>>>(Y, gamma, beta);
}